// Round 2
// baseline (650.219 us; speedup 1.0000x reference)
//
#include <hip/hip_runtime.h>
#include <hip/hip_bf16.h>
#include <cstdint>

typedef __bf16 bf16;
typedef bf16 bf16x4 __attribute__((ext_vector_type(4)));
typedef bf16 bf16x8 __attribute__((ext_vector_type(8)));
typedef float f32x4 __attribute__((ext_vector_type(4)));

#define NB 16
#define NL 1025
#define NDIM 1024
#define NHEADS 16
#define NCOND 256
#define NBH (NB*NHEADS)       // 256
#define NML (NB*NL)           // 16400
#define LP 1056               // padded kv length for v^T rows
#define QTILES 17             // ceil(1025/64)
#define QSCALE (0.125f * 1.44269504088896340736f)  // sm_scale * log2(e)

__device__ __forceinline__ void gload16(const void* g, void* l) {
  __builtin_amdgcn_global_load_lds(
      (const __attribute__((address_space(1))) void*)(uintptr_t)g,
      (__attribute__((address_space(3))) void*)(uintptr_t)l,
      16, 0, 0);
}

// ---------------- scale = cond @ w_norm^T + 1 ----------------
__global__ __launch_bounds__(256) void k_scale(const float* __restrict__ cond,
                                               const float* __restrict__ wn,
                                               float* __restrict__ scl) {
  __shared__ float cs[NCOND];
  const int b = blockIdx.x, t = threadIdx.x;
  cs[t] = cond[b * NCOND + t];
  __syncthreads();
#pragma unroll
  for (int dd = 0; dd < 4; ++dd) {
    const int d = t * 4 + dd;
    const float4* w = (const float4*)(wn + (size_t)d * NCOND);
    float acc = 1.0f;
    for (int c4 = 0; c4 < NCOND / 4; ++c4) {
      float4 wv = w[c4];
      acc += wv.x * cs[c4*4] + wv.y * cs[c4*4+1] + wv.z * cs[c4*4+2] + wv.w * cs[c4*4+3];
    }
    scl[b * NDIM + d] = acc;
  }
}

// ---------------- fp32 -> bf16 cast ----------------
__global__ __launch_bounds__(256) void k_cast(const float* __restrict__ src,
                                              bf16* __restrict__ dst, int n) {
  const int i = (blockIdx.x * 256 + threadIdx.x) * 4;
  if (i < n) {
    float4 v = *(const float4*)(src + i);
    bf16x4 o;
    o[0] = (bf16)v.x; o[1] = (bf16)v.y; o[2] = (bf16)v.z; o[3] = (bf16)v.w;
    *(bf16x4*)(dst + i) = o;
  }
}

// ---------------- RMSNorm * scale -> xn (bf16) ----------------
__global__ __launch_bounds__(256) void k_rmsnorm(const float* __restrict__ x,
                                                 const float* __restrict__ scl,
                                                 bf16* __restrict__ xn) {
  const int row = blockIdx.x, t = threadIdx.x;
  const int b = row / NL;
  const float* xr = x + (size_t)row * NDIM;
  float4 v = *(const float4*)(xr + t * 4);
  float ss = v.x*v.x + v.y*v.y + v.z*v.z + v.w*v.w;
#pragma unroll
  for (int o = 1; o < 64; o <<= 1) ss += __shfl_xor(ss, o);
  __shared__ float red[4];
  if ((t & 63) == 0) red[t >> 6] = ss;
  __syncthreads();
  const float tot = red[0] + red[1] + red[2] + red[3];
  const float rn = rsqrtf(tot * (1.0f / NDIM) + 1e-6f);
  const float4 sc = *(const float4*)(scl + b * NDIM + t * 4);
  bf16x4 o4;
  o4[0] = (bf16)(v.x * sc.x * rn);
  o4[1] = (bf16)(v.y * sc.y * rn);
  o4[2] = (bf16)(v.z * sc.z * rn);
  o4[3] = (bf16)(v.w * sc.w * rn);
  *(bf16x4*)(xn + (size_t)row * NDIM + t * 4) = o4;
}

// ---------------- GEMM: C[m,n] = sum_k A[m,k]*B[n,k]  (both row-major, B^T form) ----
// EPI=0: store bf16; EPI=1: store f32 + skip add
template <int EPI>
__global__ __launch_bounds__(256) void k_gemm(const bf16* __restrict__ A,
                                              const bf16* __restrict__ Bm,
                                              int M, int N, int K,
                                              bf16* __restrict__ Cb,
                                              float* __restrict__ Cf,
                                              const float* __restrict__ skip) {
  __shared__ bf16 Als[128 * 64];
  __shared__ bf16 Bls[128 * 64];
  const int t = threadIdx.x;
  const int wave = t >> 6, lane = t & 63;
  const int g = lane >> 4, c = lane & 15;
  const int wm = wave >> 1, wn_ = wave & 1;
  const int m0 = blockIdx.y * 128, n0 = blockIdx.x * 128;

  const int srow = lane >> 3;                 // row within 8-row segment
  const int scol = ((lane & 7) ^ srow) * 8;   // pre-swizzled source granule

  f32x4 acc[4][4];
#pragma unroll
  for (int i = 0; i < 4; ++i)
#pragma unroll
    for (int j = 0; j < 4; ++j) acc[i][j] = f32x4{0.f, 0.f, 0.f, 0.f};

  for (int k0 = 0; k0 < K; k0 += 64) {
    __syncthreads();
#pragma unroll
    for (int i = 0; i < 4; ++i) {
      const int seg = wave * 4 + i;
      int arow = m0 + seg * 8 + srow;
      if (arow >= M) arow = M - 1;
      gload16(A + (size_t)arow * K + k0 + scol, &Als[seg * 512]);
      const int brow = n0 + seg * 8 + srow;
      gload16(Bm + (size_t)brow * K + k0 + scol, &Bls[seg * 512]);
    }
    __syncthreads();
#pragma unroll
    for (int kc = 0; kc < 2; ++kc) {
      bf16x8 af[4], bfr[4];
#pragma unroll
      for (int mi = 0; mi < 4; ++mi) {
        const int r = wm * 64 + mi * 16 + c;
        const int gg = ((kc * 4 + g) ^ (c & 7)) * 8;
        af[mi] = *(const bf16x8*)&Als[r * 64 + gg];
      }
#pragma unroll
      for (int ni = 0; ni < 4; ++ni) {
        const int r = wn_ * 64 + ni * 16 + c;
        const int gg = ((kc * 4 + g) ^ (c & 7)) * 8;
        bfr[ni] = *(const bf16x8*)&Bls[r * 64 + gg];
      }
#pragma unroll
      for (int mi = 0; mi < 4; ++mi)
#pragma unroll
        for (int ni = 0; ni < 4; ++ni)
          acc[mi][ni] = __builtin_amdgcn_mfma_f32_16x16x32_bf16(af[mi], bfr[ni], acc[mi][ni], 0, 0, 0);
    }
  }

#pragma unroll
  for (int mi = 0; mi < 4; ++mi) {
    const int rb = m0 + wm * 64 + mi * 16 + g * 4;
#pragma unroll
    for (int ni = 0; ni < 4; ++ni) {
      const int col = n0 + wn_ * 64 + ni * 16 + c;
#pragma unroll
      for (int j = 0; j < 4; ++j) {
        const int row = rb + j;
        if (row < M) {
          const size_t idx = (size_t)row * N + col;
          if (EPI == 0) Cb[idx] = (bf16)acc[mi][ni][j];
          else          Cf[idx] = acc[mi][ni][j] + skip[idx];
        }
      }
    }
  }
}

// ---------------- RoPE + layout reorg ----------------
// qkv: (B*L, 3*1024) bf16  ->  qr/kr: [bh][l][64] bf16 (q pre-scaled), vt: [bh][64][LP] bf16
// 256 threads: row = t>>2 (64 rows), each thread covers 16 contiguous cols c0=(t&3)*16.
__global__ __launch_bounds__(256) void k_rope(const bf16* __restrict__ qkv,
                                              const float* __restrict__ cosT,
                                              const float* __restrict__ sinT,
                                              bf16* __restrict__ qr,
                                              bf16* __restrict__ kr,
                                              bf16* __restrict__ vt) {
  __shared__ bf16 tq[64][64], tk[64][64], tv[64][64];
  const int blk = blockIdx.x;
  const int lt = blk % QTILES, bh = blk / QTILES;
  const int b = bh >> 4, h = bh & 15;
  const int l0 = lt * 64;
  const int t = threadIdx.x;
  const int row = t >> 2, ch = t & 3;
  const int c0 = ch * 16;
  const int l = l0 + row;
  const int lc = (l < NL) ? l : (NL - 1);
  const size_t base = ((size_t)(b * NL + lc)) * 3072 + h * 64 + c0;
  *(bf16x8*)&tq[row][c0]     = *(const bf16x8*)(qkv + base);
  *(bf16x8*)&tq[row][c0 + 8] = *(const bf16x8*)(qkv + base + 8);
  *(bf16x8*)&tk[row][c0]     = *(const bf16x8*)(qkv + base + 1024);
  *(bf16x8*)&tk[row][c0 + 8] = *(const bf16x8*)(qkv + base + 1032);
  *(bf16x8*)&tv[row][c0]     = *(const bf16x8*)(qkv + base + 2048);
  *(bf16x8*)&tv[row][c0 + 8] = *(const bf16x8*)(qkv + base + 2056);
  __syncthreads();

  if (l < NL) {
    bf16x8 vq0, vq1, vk0, vk1;
#pragma unroll
    for (int j = 0; j < 16; ++j) {
      const int d = c0 + j;
      float qv, kv;
      if (d < 16) {
        const float cf = cosT[l * 16 + d], sf = sinT[l * 16 + d];
        qv = (float)tq[row][d] * cf - (float)tq[row][d + 16] * sf;
        kv = (float)tk[row][d] * cf - (float)tk[row][d + 16] * sf;
      } else if (d < 32) {
        const float cf = cosT[l * 16 + d - 16], sf = sinT[l * 16 + d - 16];
        qv = (float)tq[row][d] * cf + (float)tq[row][d - 16] * sf;
        kv = (float)tk[row][d] * cf + (float)tk[row][d - 16] * sf;
      } else {
        qv = (float)tq[row][d];
        kv = (float)tk[row][d];
      }
      if (j < 8) { vq0[j] = (bf16)(qv * QSCALE); vk0[j] = (bf16)kv; }
      else       { vq1[j - 8] = (bf16)(qv * QSCALE); vk1[j - 8] = (bf16)kv; }
    }
    const size_t ob = ((size_t)bh * NL + l) * 64 + c0;
    *(bf16x8*)(qr + ob)     = vq0;
    *(bf16x8*)(qr + ob + 8) = vq1;
    *(bf16x8*)(kr + ob)     = vk0;
    *(bf16x8*)(kr + ob + 8) = vk1;
  }

  // V transpose: thread t handles column d = t>>2, l-segment seg = t&3 (16 values)
  const int d = t >> 2, seg = t & 3;
  const int lb = l0 + seg * 16;
  if (lb + 15 < LP) {
    bf16x8 p0, p1;
#pragma unroll
    for (int i = 0; i < 8; ++i) p0[i] = tv[seg * 16 + i][d];
#pragma unroll
    for (int i = 0; i < 8; ++i) p1[i] = tv[seg * 16 + 8 + i][d];
    const size_t vb = ((size_t)bh * 64 + d) * LP + lb;
    *(bf16x8*)(vt + vb) = p0;
    *(bf16x8*)(vt + vb + 8) = p1;
  }
}

// ---------------- causal flash attention ----------------
__global__ __launch_bounds__(256) void k_attn(const bf16* __restrict__ qr,
                                              const bf16* __restrict__ kr,
                                              const bf16* __restrict__ vt,
                                              bf16* __restrict__ oa) {
  __shared__ bf16 plds[4][16][40];  // per-wave P tile, stride 40 to dodge bank conflicts
  const int blk = blockIdx.x;
  const int qt = blk % QTILES, bh = blk / QTILES;
  const int b = bh >> 4, h = bh & 15;
  const int lane = threadIdx.x & 63, wave = threadIdx.x >> 6;
  const int g = lane >> 4, c = lane & 15;
  const int q0 = qt * 64 + wave * 16;
  if (q0 >= NL) return;
  bf16 (*P)[40] = plds[wave];
  const bf16* qb = qr + (size_t)bh * NL * 64;
  const bf16* kb = kr + (size_t)bh * NL * 64;
  const bf16* vb = vt + (size_t)bh * 64 * LP;

  int qrl = q0 + c; if (qrl >= NL) qrl = NL - 1;
  const bf16x8 aq0 = *(const bf16x8*)(qb + (size_t)qrl * 64 + g * 8);
  const bf16x8 aq1 = *(const bf16x8*)(qb + (size_t)qrl * 64 + 32 + g * 8);

  f32x4 o0 = {0,0,0,0}, o1 = {0,0,0,0}, o2 = {0,0,0,0}, o3 = {0,0,0,0};
  float ms[4], ls[4];
#pragma unroll
  for (int j = 0; j < 4; ++j) { ms[j] = -1e30f; ls[j] = 0.f; }

  const int nt0 = (q0 + 16 + 31) >> 5;
  const int ntc = (NL + 31) >> 5;
  const int nt = nt0 < ntc ? nt0 : ntc;

  for (int tk = 0; tk < nt; ++tk) {
    const int kv0 = tk * 32;
    int r0 = kv0 + c;      if (r0 >= NL) r0 = NL - 1;
    int r1 = kv0 + 16 + c; if (r1 >= NL) r1 = NL - 1;
    const bf16x8 bk00 = *(const bf16x8*)(kb + (size_t)r0 * 64 + g * 8);
    const bf16x8 bk01 = *(const bf16x8*)(kb + (size_t)r0 * 64 + 32 + g * 8);
    const bf16x8 bk10 = *(const bf16x8*)(kb + (size_t)r1 * 64 + g * 8);
    const bf16x8 bk11 = *(const bf16x8*)(kb + (size_t)r1 * 64 + 32 + g * 8);
    f32x4 s0 = {0,0,0,0}, s1 = {0,0,0,0};
    s0 = __builtin_amdgcn_mfma_f32_16x16x32_bf16(aq0, bk00, s0, 0, 0, 0);
    s0 = __builtin_amdgcn_mfma_f32_16x16x32_bf16(aq1, bk01, s0, 0, 0, 0);
    s1 = __builtin_amdgcn_mfma_f32_16x16x32_bf16(aq0, bk10, s1, 0, 0, 0);
    s1 = __builtin_amdgcn_mfma_f32_16x16x32_bf16(aq1, bk11, s1, 0, 0, 0);

    const bool needmask = (kv0 + 31 > q0);
    float p0[4], p1[4];
#pragma unroll
    for (int j = 0; j < 4; ++j) {
      float v0 = s0[j], v1 = s1[j];
      if (needmask) {
        const int grow = q0 + g * 4 + j;
        if (kv0 + c > grow)      v0 = -1e30f;
        if (kv0 + 16 + c > grow) v1 = -1e30f;
      }
      float pm = fmaxf(v0, v1);
      pm = fmaxf(pm, __shfl_xor(pm, 1));
      pm = fmaxf(pm, __shfl_xor(pm, 2));
      pm = fmaxf(pm, __shfl_xor(pm, 4));
      pm = fmaxf(pm, __shfl_xor(pm, 8));
      const float mn = fmaxf(ms[j], pm);
      const float al = exp2f(ms[j] - mn);
      ms[j] = mn;
      v0 = exp2f(v0 - mn);
      v1 = exp2f(v1 - mn);
      float rs = v0 + v1;
      rs += __shfl_xor(rs, 1);
      rs += __shfl_xor(rs, 2);
      rs += __shfl_xor(rs, 4);
      rs += __shfl_xor(rs, 8);
      ls[j] = ls[j] * al + rs;
      o0[j] *= al; o1[j] *= al; o2[j] *= al; o3[j] *= al;
      p0[j] = v0; p1[j] = v1;
    }
#pragma unroll
    for (int j = 0; j < 4; ++j) {
      P[g * 4 + j][c]      = (bf16)p0[j];
      P[g * 4 + j][16 + c] = (bf16)p1[j];
    }
    const bf16x8 pa = *(const bf16x8*)&P[c][g * 8];
    const bf16x8 bv0 = *(const bf16x8*)(vb + (size_t)(c) * LP      + kv0 + g * 8);
    const bf16x8 bv1 = *(const bf16x8*)(vb + (size_t)(16 + c) * LP + kv0 + g * 8);
    const bf16x8 bv2 = *(const bf16x8*)(vb + (size_t)(32 + c) * LP + kv0 + g * 8);
    const bf16x8 bv3 = *(const bf16x8*)(vb + (size_t)(48 + c) * LP + kv0 + g * 8);
    o0 = __builtin_amdgcn_mfma_f32_16x16x32_bf16(pa, bv0, o0, 0, 0, 0);
    o1 = __builtin_amdgcn_mfma_f32_16x16x32_bf16(pa, bv1, o1, 0, 0, 0);
    o2 = __builtin_amdgcn_mfma_f32_16x16x32_bf16(pa, bv2, o2, 0, 0, 0);
    o3 = __builtin_amdgcn_mfma_f32_16x16x32_bf16(pa, bv3, o3, 0, 0, 0);
  }

#pragma unroll
  for (int j = 0; j < 4; ++j) {
    const int row = q0 + g * 4 + j;
    if (row < NL) {
      const float inv = 1.0f / ls[j];
      const size_t ob = (size_t)(b * NL + row) * NDIM + h * 64;
      oa[ob + c]      = (bf16)(o0[j] * inv);
      oa[ob + 16 + c] = (bf16)(o1[j] * inv);
      oa[ob + 32 + c] = (bf16)(o2[j] * inv);
      oa[ob + 48 + c] = (bf16)(o3[j] * inv);
    }
  }
}

extern "C" void kernel_launch(void* const* d_in, const int* in_sizes, int n_in,
                              void* d_out, int out_size, void* d_ws, size_t ws_size,
                              hipStream_t stream) {
  const float* x     = (const float*)d_in[0];
  const float* cond  = (const float*)d_in[1];
  const float* wnorm = (const float*)d_in[2];
  const float* wqkv  = (const float*)d_in[3];
  const float* wout  = (const float*)d_in[4];
  const float* cosT  = (const float*)d_in[5];
  const float* sinT  = (const float*)d_in[6];
  float* out = (float*)d_out;
  char* ws = (char*)d_ws;

  float* s_scl = (float*)(ws);                    //    65,536 B
  bf16*  s_wq  = (bf16*)(ws + 65536);             // 6,291,456 B
  bf16*  s_wo  = (bf16*)(ws + 6356992);           // 2,097,152 B
  bf16*  s_xn  = (bf16*)(ws + 8454144);           // 33,587,200 B (reused as attn out)
  bf16*  s_qkv = (bf16*)(ws + 42041344);          // 100,761,600 B
  bf16*  s_qr  = (bf16*)(ws + 142802944);         // 33,587,200 B
  bf16*  s_kr  = (bf16*)(ws + 176390144);         // 33,587,200 B
  bf16*  s_vt  = (bf16*)(ws + 209977344);         // 34,603,008 B -> end 244,580,352 B

  k_scale<<<NB, 256, 0, stream>>>(cond, wnorm, s_scl);
  k_cast<<<3072, 256, 0, stream>>>(wqkv, s_wq, 3 * NDIM * NDIM);
  k_cast<<<1024, 256, 0, stream>>>(wout, s_wo, NDIM * NDIM);
  k_rmsnorm<<<NML, 256, 0, stream>>>(x, s_scl, s_xn);
  k_gemm<0><<<dim3(24, 129), 256, 0, stream>>>(s_xn, s_wq, NML, 3 * NDIM, NDIM,
                                               s_qkv, nullptr, nullptr);
  k_rope<<<NBH * QTILES, 256, 0, stream>>>(s_qkv, cosT, sinT, s_qr, s_kr, s_vt);
  k_attn<<<NBH * QTILES, 256, 0, stream>>>(s_qr, s_kr, s_vt, s_xn);
  k_gemm<1><<<dim3(8, 129), 256, 0, stream>>>(s_xn, s_wo, NML, NDIM, NDIM,
                                              nullptr, out, x);
}